// Round 1
// baseline (668.233 us; speedup 1.0000x reference)
//
#include <hip/hip_runtime.h>
#include <hip/hip_bf16.h>
#include <math.h>

#define NROWS 8192
#define DDIM  1024
#define BT    128
#define BK    64
#define MARGIN 0.3f

typedef __attribute__((ext_vector_type(4))) float  f32x4;
typedef __attribute__((ext_vector_type(8))) __bf16 bf16x8;

__device__ __forceinline__ unsigned f2bf_bits(float f) {
  unsigned u = __float_as_uint(f);
  u += 0x7fffu + ((u >> 16) & 1u);   // RNE
  return u >> 16;
}

// ---------------- Kernel 1: inverse row norms for x and y -------------------
__global__ __launch_bounds__(256) void norm_kernel(const float* __restrict__ x,
                                                   const float* __restrict__ y,
                                                   float* __restrict__ invn) {
  int wid  = (int)((blockIdx.x * blockDim.x + threadIdx.x) >> 6);  // 0..16383
  int lane = threadIdx.x & 63;
  const float* src = (wid < NROWS) ? x : y;
  int row = (wid < NROWS) ? wid : (wid - NROWS);
  const float4* p = (const float4*)(src + (size_t)row * DDIM);
  float s = 0.f;
#pragma unroll
  for (int a = 0; a < 4; ++a) {
    float4 v = p[a * 64 + lane];
    s = fmaf(v.x, v.x, s); s = fmaf(v.y, v.y, s);
    s = fmaf(v.z, v.z, s); s = fmaf(v.w, v.w, s);
  }
#pragma unroll
  for (int m = 1; m < 64; m <<= 1) s += __shfl_xor(s, m, 64);
  if (lane == 0) invn[wid] = 1.0f / fmaxf(sqrtf(s), 1e-8f);
}

// ------- Kernel 2: fused S-tile GEMM + exp + row/col reduce + diag ----------
__global__ __launch_bounds__(256) void gemm_kernel(const float* __restrict__ x,
                                                   const float* __restrict__ y,
                                                   const float* __restrict__ invn,
                                                   float* __restrict__ rowsum,
                                                   float* __restrict__ colsum,
                                                   float* __restrict__ diagv) {
  __shared__ alignas(16) unsigned short As[BT * BK];  // xn tile [row][k] bf16
  __shared__ alignas(16) unsigned short Bs[BT * BK];  // yn tile [col][k] bf16
  __shared__ float red_row[BT];
  __shared__ float red_col[BT];

  const int tid  = threadIdx.x;
  const int bi   = blockIdx.y;  // S row block (x rows)
  const int bj   = blockIdx.x;  // S col block (y rows)
  const int lane = tid & 63;
  const int wave = tid >> 6;
  const int wr   = wave >> 1, wc = wave & 1;   // wave covers 64x64 quadrant
  const int quad = lane >> 4, l15 = lane & 15;

  // staging: access a in 0..7 -> row = a*16 + (tid>>4), float4-col = tid&15
  const int srow = tid >> 4;
  const int sc4  = tid & 15;

  if (tid < BT) red_row[tid] = 0.f; else red_col[tid - BT] = 0.f;

  float ainv[8], binv[8];
#pragma unroll
  for (int a = 0; a < 8; ++a) {
    ainv[a] = invn[bi * BT + a * 16 + srow];
    binv[a] = invn[NROWS + bj * BT + a * 16 + srow];
  }

  f32x4 acc[4][4];
#pragma unroll
  for (int i = 0; i < 4; ++i)
#pragma unroll
    for (int j = 0; j < 4; ++j) acc[i][j] = (f32x4){0.f, 0.f, 0.f, 0.f};

  for (int k0 = 0; k0 < DDIM; k0 += BK) {
#pragma unroll
    for (int a = 0; a < 8; ++a) {
      int row = a * 16 + srow;
      float4 va = *(const float4*)(x + (size_t)(bi * BT + row) * DDIM + k0 + sc4 * 4);
      float4 vb = *(const float4*)(y + (size_t)(bj * BT + row) * DDIM + k0 + sc4 * 4);
      float sa = ainv[a], sb = binv[a];
      unsigned long long pa =
          (unsigned long long)f2bf_bits(va.x * sa) |
          ((unsigned long long)f2bf_bits(va.y * sa) << 16) |
          ((unsigned long long)f2bf_bits(va.z * sa) << 32) |
          ((unsigned long long)f2bf_bits(va.w * sa) << 48);
      unsigned long long pb =
          (unsigned long long)f2bf_bits(vb.x * sb) |
          ((unsigned long long)f2bf_bits(vb.y * sb) << 16) |
          ((unsigned long long)f2bf_bits(vb.z * sb) << 32) |
          ((unsigned long long)f2bf_bits(vb.w * sb) << 48);
      *(unsigned long long*)&As[row * BK + sc4 * 4] = pa;
      *(unsigned long long*)&Bs[row * BK + sc4 * 4] = pb;
    }
    __syncthreads();
#pragma unroll
    for (int kk = 0; kk < BK; kk += 32) {
      bf16x8 af[4], bf[4];
#pragma unroll
      for (int f = 0; f < 4; ++f) {
        af[f] = *(const bf16x8*)&As[(wr * 64 + f * 16 + l15) * BK + kk + quad * 8];
        bf[f] = *(const bf16x8*)&Bs[(wc * 64 + f * 16 + l15) * BK + kk + quad * 8];
      }
#pragma unroll
      for (int fr = 0; fr < 4; ++fr)
#pragma unroll
        for (int fc = 0; fc < 4; ++fc)
          acc[fr][fc] = __builtin_amdgcn_mfma_f32_16x16x32_bf16(af[fr], bf[fc], acc[fr][fc], 0, 0, 0);
    }
    __syncthreads();
  }

  // ---- epilogue ----
  // diag: lane holds rows quad*4+r, col l15 of each 16x16 frag
  if (bi == bj && wr == wc && (l15 >> 2) == quad) {
    int r = l15 & 3;
#pragma unroll
    for (int f = 0; f < 4; ++f)
      diagv[bi * BT + wr * 64 + f * 16 + l15] = acc[f][f][r];
  }

  float racc[4][4];  // [fr][r] row partials (this lane's col)
  float cacc[4];     // [fc]    col partials (this quad's 16 rows)
#pragma unroll
  for (int i = 0; i < 4; ++i) {
    cacc[i] = 0.f;
#pragma unroll
    for (int j = 0; j < 4; ++j) racc[i][j] = 0.f;
  }
#pragma unroll
  for (int fr = 0; fr < 4; ++fr)
#pragma unroll
    for (int fc = 0; fc < 4; ++fc) {
      f32x4 v = acc[fr][fc];
#pragma unroll
      for (int r = 0; r < 4; ++r) {
        float e = __expf(v[r]);
        racc[fr][r] += e;
        cacc[fc]    += e;
      }
    }
  // reduce rows across the 16 cols (lanes sharing quad)
#pragma unroll
  for (int m = 1; m <= 8; m <<= 1)
#pragma unroll
    for (int fr = 0; fr < 4; ++fr)
#pragma unroll
      for (int r = 0; r < 4; ++r) racc[fr][r] += __shfl_xor(racc[fr][r], m, 64);
  if (l15 == 0)
#pragma unroll
    for (int fr = 0; fr < 4; ++fr)
#pragma unroll
      for (int r = 0; r < 4; ++r)
        atomicAdd(&red_row[wr * 64 + fr * 16 + quad * 4 + r], racc[fr][r]);
  // reduce cols across the 4 quads
#pragma unroll
  for (int m = 16; m <= 32; m <<= 1)
#pragma unroll
    for (int fc = 0; fc < 4; ++fc) cacc[fc] += __shfl_xor(cacc[fc], m, 64);
  if (quad == 0)
#pragma unroll
    for (int fc = 0; fc < 4; ++fc)
      atomicAdd(&red_col[wc * 64 + fc * 16 + l15], cacc[fc]);

  __syncthreads();
  if (tid < BT) atomicAdd(&rowsum[bi * BT + tid], red_row[tid]);
  else          atomicAdd(&colsum[bj * BT + (tid - BT)], red_col[tid - BT]);
}

// ---------------- Kernel 3: final loss --------------------------------------
__global__ __launch_bounds__(256) void finalize_kernel(const float* __restrict__ rowsum,
                                                       const float* __restrict__ colsum,
                                                       const float* __restrict__ diagv,
                                                       float* __restrict__ out) {
  float s = 0.f;
  for (int i = threadIdx.x; i < NROWS; i += 256) {
    float d  = diagv[i];
    float ed = __expf(d);
    float m1 = __expf(d - MARGIN);
    float negR = rowsum[i] - ed;
    float negC = colsum[i] - ed;
    s += __logf((m1 + negR) / m1) + __logf((m1 + negC) / m1);
  }
  __shared__ float red[4];
#pragma unroll
  for (int m = 1; m < 64; m <<= 1) s += __shfl_xor(s, m, 64);
  if ((threadIdx.x & 63) == 0) red[threadIdx.x >> 6] = s;
  __syncthreads();
  if (threadIdx.x == 0)
    out[0] = (red[0] + red[1] + red[2] + red[3]) / (float)NROWS;
}

extern "C" void kernel_launch(void* const* d_in, const int* in_sizes, int n_in,
                              void* d_out, int out_size, void* d_ws, size_t ws_size,
                              hipStream_t stream) {
  const float* x = (const float*)d_in[0];
  const float* y = (const float*)d_in[1];
  float* out = (float*)d_out;

  char* ws = (char*)d_ws;
  float* invn   = (float*)ws;                       // 16384 f32
  float* rowsum = (float*)(ws + 16384 * 4);         // 8192 f32
  float* colsum = rowsum + NROWS;                   // 8192 f32
  float* diagv  = colsum + NROWS;                   // 8192 f32  (total 160 KB)

  hipMemsetAsync(rowsum, 0, 2 * NROWS * sizeof(float), stream);
  norm_kernel<<<dim3((2 * NROWS) / 4 / 64), 256, 0, stream>>>(x, y, invn);
  gemm_kernel<<<dim3(NROWS / BT, NROWS / BT), 256, 0, stream>>>(x, y, invn, rowsum, colsum, diagv);
  finalize_kernel<<<dim3(1), 256, 0, stream>>>(rowsum, colsum, diagv, out);
}

// Round 2
// 314.936 us; speedup vs baseline: 2.1218x; 2.1218x over previous
//
#include <hip/hip_runtime.h>
#include <hip/hip_bf16.h>
#include <math.h>

#define NROWS 8192
#define DDIM  1024
#define BT    128
#define BK    64
#define MARGIN 0.3f

typedef __attribute__((ext_vector_type(4))) float  f32x4;
typedef __attribute__((ext_vector_type(8))) __bf16 bf16x8;

__device__ __forceinline__ unsigned f2bf_bits(float f) {
  unsigned u = __float_as_uint(f);
  u += 0x7fffu + ((u >> 16) & 1u);   // RNE
  return u >> 16;
}

// ============================ FAST PATH =====================================
// Kernel A: fused row-norm + bf16 convert: xn/yn = rownormalize(x/y) in bf16.
__global__ __launch_bounds__(256) void normconv_kernel(const float* __restrict__ x,
                                                       const float* __restrict__ y,
                                                       unsigned short* __restrict__ xn,
                                                       unsigned short* __restrict__ yn) {
  int wid  = blockIdx.x * 4 + (threadIdx.x >> 6);   // 0..16383, one wave per row
  int lane = threadIdx.x & 63;
  const float* src;
  unsigned short* dst;
  int row;
  if (wid < NROWS) { src = x; dst = xn; row = wid; }
  else             { src = y; dst = yn; row = wid - NROWS; }
  const float4* p = (const float4*)(src + (size_t)row * DDIM);
  float4 v[4];
  float s = 0.f;
#pragma unroll
  for (int a = 0; a < 4; ++a) {
    v[a] = p[a * 64 + lane];
    s = fmaf(v[a].x, v[a].x, s); s = fmaf(v[a].y, v[a].y, s);
    s = fmaf(v[a].z, v[a].z, s); s = fmaf(v[a].w, v[a].w, s);
  }
#pragma unroll
  for (int m = 1; m < 64; m <<= 1) s += __shfl_xor(s, m, 64);
  float inv = 1.0f / fmaxf(sqrtf(s), 1e-8f);
  unsigned long long* d8 = (unsigned long long*)(dst + (size_t)row * DDIM);
#pragma unroll
  for (int a = 0; a < 4; ++a) {
    unsigned long long pk =
        (unsigned long long)f2bf_bits(v[a].x * inv) |
        ((unsigned long long)f2bf_bits(v[a].y * inv) << 16) |
        ((unsigned long long)f2bf_bits(v[a].z * inv) << 32) |
        ((unsigned long long)f2bf_bits(v[a].w * inv) << 48);
    d8[a * 64 + lane] = pk;
  }
}

// Kernel B: m97-style GEMM on precomputed bf16, global_load_lds staging,
// fused exp + row/col reduction + diagonal extraction epilogue.
__global__ __launch_bounds__(256) void gemm_bf_kernel(const unsigned short* __restrict__ xn,
                                                      const unsigned short* __restrict__ yn,
                                                      float* __restrict__ rowsum,
                                                      float* __restrict__ colsum,
                                                      float* __restrict__ diagv) {
  __shared__ alignas(16) unsigned short As[BT * BK];  // [row][k] bf16, stride 64
  __shared__ alignas(16) unsigned short Bs[BT * BK];
  __shared__ float red_row[BT];
  __shared__ float red_col[BT];

  const int tid  = threadIdx.x;
  const int bi   = blockIdx.y;
  const int bj   = blockIdx.x;
  const int lane = tid & 63;
  const int wave = tid >> 6;
  const int wr   = wave >> 1, wc = wave & 1;
  const int quad = lane >> 4, l15 = lane & 15;

  if (tid < BT) red_row[tid] = 0.f; else red_col[tid - BT] = 0.f;

  // staging: wave covers rows [wave*32, wave*32+32), 4 issues of 8 rows each;
  // lane l: local row l/8, 16B col-group l%8.  LDS dest = base + lane*16 (HW).
  const int r_l = lane >> 3;
  const int cg  = lane & 7;
  const unsigned short* ga =
      xn + (size_t)(bi * BT + wave * 32 + r_l) * DDIM + cg * 8;
  const unsigned short* gb =
      yn + (size_t)(bj * BT + wave * 32 + r_l) * DDIM + cg * 8;

  f32x4 acc[4][4];
#pragma unroll
  for (int i = 0; i < 4; ++i)
#pragma unroll
    for (int j = 0; j < 4; ++j) acc[i][j] = (f32x4){0.f, 0.f, 0.f, 0.f};

  for (int k0 = 0; k0 < DDIM; k0 += BK) {
#pragma unroll
    for (int a = 0; a < 4; ++a) {
      __builtin_amdgcn_global_load_lds(
          (const __attribute__((address_space(1))) unsigned int*)(ga + (size_t)a * 8 * DDIM + k0),
          (__attribute__((address_space(3))) unsigned int*)&As[(wave * 32 + a * 8) * BK],
          16, 0, 0);
      __builtin_amdgcn_global_load_lds(
          (const __attribute__((address_space(1))) unsigned int*)(gb + (size_t)a * 8 * DDIM + k0),
          (__attribute__((address_space(3))) unsigned int*)&Bs[(wave * 32 + a * 8) * BK],
          16, 0, 0);
    }
    __syncthreads();
#pragma unroll
    for (int kk = 0; kk < BK; kk += 32) {
      bf16x8 af[4], bf[4];
#pragma unroll
      for (int f = 0; f < 4; ++f) {
        af[f] = *(const bf16x8*)&As[(wr * 64 + f * 16 + l15) * BK + kk + quad * 8];
        bf[f] = *(const bf16x8*)&Bs[(wc * 64 + f * 16 + l15) * BK + kk + quad * 8];
      }
#pragma unroll
      for (int fr = 0; fr < 4; ++fr)
#pragma unroll
        for (int fc = 0; fc < 4; ++fc)
          acc[fr][fc] = __builtin_amdgcn_mfma_f32_16x16x32_bf16(af[fr], bf[fc], acc[fr][fc], 0, 0, 0);
    }
    __syncthreads();
  }

  // ---- epilogue (validated in R1) ----
  if (bi == bj && wr == wc && (l15 >> 2) == quad) {
    int r = l15 & 3;
#pragma unroll
    for (int f = 0; f < 4; ++f)
      diagv[bi * BT + wr * 64 + f * 16 + l15] = acc[f][f][r];
  }

  float racc[4][4];
  float cacc[4];
#pragma unroll
  for (int i = 0; i < 4; ++i) {
    cacc[i] = 0.f;
#pragma unroll
    for (int j = 0; j < 4; ++j) racc[i][j] = 0.f;
  }
#pragma unroll
  for (int fr = 0; fr < 4; ++fr)
#pragma unroll
    for (int fc = 0; fc < 4; ++fc) {
      f32x4 v = acc[fr][fc];
#pragma unroll
      for (int r = 0; r < 4; ++r) {
        float e = __expf(v[r]);
        racc[fr][r] += e;
        cacc[fc]    += e;
      }
    }
#pragma unroll
  for (int m = 1; m <= 8; m <<= 1)
#pragma unroll
    for (int fr = 0; fr < 4; ++fr)
#pragma unroll
      for (int r = 0; r < 4; ++r) racc[fr][r] += __shfl_xor(racc[fr][r], m, 64);
  if (l15 == 0)
#pragma unroll
    for (int fr = 0; fr < 4; ++fr)
#pragma unroll
      for (int r = 0; r < 4; ++r)
        atomicAdd(&red_row[wr * 64 + fr * 16 + quad * 4 + r], racc[fr][r]);
#pragma unroll
  for (int m = 16; m <= 32; m <<= 1)
#pragma unroll
    for (int fc = 0; fc < 4; ++fc) cacc[fc] += __shfl_xor(cacc[fc], m, 64);
  if (quad == 0)
#pragma unroll
    for (int fc = 0; fc < 4; ++fc)
      atomicAdd(&red_col[wc * 64 + fc * 16 + l15], cacc[fc]);

  __syncthreads();
  if (tid < BT) atomicAdd(&rowsum[bi * BT + tid], red_row[tid]);
  else          atomicAdd(&colsum[bj * BT + (tid - BT)], red_col[tid - BT]);
}

// ============================ FALLBACK PATH (R1, known-good) ================
__global__ __launch_bounds__(256) void norm_kernel(const float* __restrict__ x,
                                                   const float* __restrict__ y,
                                                   float* __restrict__ invn) {
  int wid  = (int)((blockIdx.x * blockDim.x + threadIdx.x) >> 6);
  int lane = threadIdx.x & 63;
  const float* src = (wid < NROWS) ? x : y;
  int row = (wid < NROWS) ? wid : (wid - NROWS);
  const float4* p = (const float4*)(src + (size_t)row * DDIM);
  float s = 0.f;
#pragma unroll
  for (int a = 0; a < 4; ++a) {
    float4 v = p[a * 64 + lane];
    s = fmaf(v.x, v.x, s); s = fmaf(v.y, v.y, s);
    s = fmaf(v.z, v.z, s); s = fmaf(v.w, v.w, s);
  }
#pragma unroll
  for (int m = 1; m < 64; m <<= 1) s += __shfl_xor(s, m, 64);
  if (lane == 0) invn[wid] = 1.0f / fmaxf(sqrtf(s), 1e-8f);
}

__global__ __launch_bounds__(256) void gemm_kernel(const float* __restrict__ x,
                                                   const float* __restrict__ y,
                                                   const float* __restrict__ invn,
                                                   float* __restrict__ rowsum,
                                                   float* __restrict__ colsum,
                                                   float* __restrict__ diagv) {
  __shared__ alignas(16) unsigned short As[BT * BK];
  __shared__ alignas(16) unsigned short Bs[BT * BK];
  __shared__ float red_row[BT];
  __shared__ float red_col[BT];

  const int tid  = threadIdx.x;
  const int bi   = blockIdx.y;
  const int bj   = blockIdx.x;
  const int lane = tid & 63;
  const int wave = tid >> 6;
  const int wr   = wave >> 1, wc = wave & 1;
  const int quad = lane >> 4, l15 = lane & 15;
  const int srow = tid >> 4;
  const int sc4  = tid & 15;

  if (tid < BT) red_row[tid] = 0.f; else red_col[tid - BT] = 0.f;

  float ainv[8], binv[8];
#pragma unroll
  for (int a = 0; a < 8; ++a) {
    ainv[a] = invn[bi * BT + a * 16 + srow];
    binv[a] = invn[NROWS + bj * BT + a * 16 + srow];
  }

  f32x4 acc[4][4];
#pragma unroll
  for (int i = 0; i < 4; ++i)
#pragma unroll
    for (int j = 0; j < 4; ++j) acc[i][j] = (f32x4){0.f, 0.f, 0.f, 0.f};

  for (int k0 = 0; k0 < DDIM; k0 += BK) {
#pragma unroll
    for (int a = 0; a < 8; ++a) {
      int row = a * 16 + srow;
      float4 va = *(const float4*)(x + (size_t)(bi * BT + row) * DDIM + k0 + sc4 * 4);
      float4 vb = *(const float4*)(y + (size_t)(bj * BT + row) * DDIM + k0 + sc4 * 4);
      float sa = ainv[a], sb = binv[a];
      unsigned long long pa =
          (unsigned long long)f2bf_bits(va.x * sa) |
          ((unsigned long long)f2bf_bits(va.y * sa) << 16) |
          ((unsigned long long)f2bf_bits(va.z * sa) << 32) |
          ((unsigned long long)f2bf_bits(va.w * sa) << 48);
      unsigned long long pb =
          (unsigned long long)f2bf_bits(vb.x * sb) |
          ((unsigned long long)f2bf_bits(vb.y * sb) << 16) |
          ((unsigned long long)f2bf_bits(vb.z * sb) << 32) |
          ((unsigned long long)f2bf_bits(vb.w * sb) << 48);
      *(unsigned long long*)&As[row * BK + sc4 * 4] = pa;
      *(unsigned long long*)&Bs[row * BK + sc4 * 4] = pb;
    }
    __syncthreads();
#pragma unroll
    for (int kk = 0; kk < BK; kk += 32) {
      bf16x8 af[4], bf[4];
#pragma unroll
      for (int f = 0; f < 4; ++f) {
        af[f] = *(const bf16x8*)&As[(wr * 64 + f * 16 + l15) * BK + kk + quad * 8];
        bf[f] = *(const bf16x8*)&Bs[(wc * 64 + f * 16 + l15) * BK + kk + quad * 8];
      }
#pragma unroll
      for (int fr = 0; fr < 4; ++fr)
#pragma unroll
        for (int fc = 0; fc < 4; ++fc)
          acc[fr][fc] = __builtin_amdgcn_mfma_f32_16x16x32_bf16(af[fr], bf[fc], acc[fr][fc], 0, 0, 0);
    }
    __syncthreads();
  }

  if (bi == bj && wr == wc && (l15 >> 2) == quad) {
    int r = l15 & 3;
#pragma unroll
    for (int f = 0; f < 4; ++f)
      diagv[bi * BT + wr * 64 + f * 16 + l15] = acc[f][f][r];
  }

  float racc[4][4];
  float cacc[4];
#pragma unroll
  for (int i = 0; i < 4; ++i) {
    cacc[i] = 0.f;
#pragma unroll
    for (int j = 0; j < 4; ++j) racc[i][j] = 0.f;
  }
#pragma unroll
  for (int fr = 0; fr < 4; ++fr)
#pragma unroll
    for (int fc = 0; fc < 4; ++fc) {
      f32x4 v = acc[fr][fc];
#pragma unroll
      for (int r = 0; r < 4; ++r) {
        float e = __expf(v[r]);
        racc[fr][r] += e;
        cacc[fc]    += e;
      }
    }
#pragma unroll
  for (int m = 1; m <= 8; m <<= 1)
#pragma unroll
    for (int fr = 0; fr < 4; ++fr)
#pragma unroll
      for (int r = 0; r < 4; ++r) racc[fr][r] += __shfl_xor(racc[fr][r], m, 64);
  if (l15 == 0)
#pragma unroll
    for (int fr = 0; fr < 4; ++fr)
#pragma unroll
      for (int r = 0; r < 4; ++r)
        atomicAdd(&red_row[wr * 64 + fr * 16 + quad * 4 + r], racc[fr][r]);
#pragma unroll
  for (int m = 16; m <= 32; m <<= 1)
#pragma unroll
    for (int fc = 0; fc < 4; ++fc) cacc[fc] += __shfl_xor(cacc[fc], m, 64);
  if (quad == 0)
#pragma unroll
    for (int fc = 0; fc < 4; ++fc)
      atomicAdd(&red_col[wc * 64 + fc * 16 + l15], cacc[fc]);

  __syncthreads();
  if (tid < BT) atomicAdd(&rowsum[bi * BT + tid], red_row[tid]);
  else          atomicAdd(&colsum[bj * BT + (tid - BT)], red_col[tid - BT]);
}

// ---------------- Final loss (shared by both paths) -------------------------
__global__ __launch_bounds__(256) void finalize_kernel(const float* __restrict__ rowsum,
                                                       const float* __restrict__ colsum,
                                                       const float* __restrict__ diagv,
                                                       float* __restrict__ out) {
  float s = 0.f;
  for (int i = threadIdx.x; i < NROWS; i += 256) {
    float d  = diagv[i];
    float ed = __expf(d);
    float m1 = __expf(d - MARGIN);
    float negR = rowsum[i] - ed;
    float negC = colsum[i] - ed;
    s += __logf((m1 + negR) / m1) + __logf((m1 + negC) / m1);
  }
  __shared__ float red[4];
#pragma unroll
  for (int m = 1; m < 64; m <<= 1) s += __shfl_xor(s, m, 64);
  if ((threadIdx.x & 63) == 0) red[threadIdx.x >> 6] = s;
  __syncthreads();
  if (threadIdx.x == 0)
    out[0] = (red[0] + red[1] + red[2] + red[3]) / (float)NROWS;
}

extern "C" void kernel_launch(void* const* d_in, const int* in_sizes, int n_in,
                              void* d_out, int out_size, void* d_ws, size_t ws_size,
                              hipStream_t stream) {
  const float* x = (const float*)d_in[0];
  const float* y = (const float*)d_in[1];
  float* out = (float*)d_out;
  char* ws = (char*)d_ws;

  const size_t bf_bytes = (size_t)NROWS * DDIM * 2;          // 16 MB each
  const size_t need_fast = 2 * bf_bytes + 3 * NROWS * 4;     // ~32 MB + 96 KB

  if (ws_size >= need_fast) {
    unsigned short* xn = (unsigned short*)ws;
    unsigned short* yn = xn + (size_t)NROWS * DDIM;
    float* rowsum = (float*)(ws + 2 * bf_bytes);
    float* colsum = rowsum + NROWS;
    float* diagv  = colsum + NROWS;
    hipMemsetAsync(rowsum, 0, 2 * NROWS * sizeof(float), stream);
    normconv_kernel<<<dim3((2 * NROWS) / 4), 256, 0, stream>>>(x, y, xn, yn);
    gemm_bf_kernel<<<dim3(NROWS / BT, NROWS / BT), 256, 0, stream>>>(xn, yn, rowsum, colsum, diagv);
    finalize_kernel<<<dim3(1), 256, 0, stream>>>(rowsum, colsum, diagv, out);
  } else {
    float* invn   = (float*)ws;
    float* rowsum = (float*)(ws + 16384 * 4);
    float* colsum = rowsum + NROWS;
    float* diagv  = colsum + NROWS;
    hipMemsetAsync(rowsum, 0, 2 * NROWS * sizeof(float), stream);
    norm_kernel<<<dim3((2 * NROWS) / 4 / 64), 256, 0, stream>>>(x, y, invn);
    gemm_kernel<<<dim3(NROWS / BT, NROWS / BT), 256, 0, stream>>>(x, y, invn, rowsum, colsum, diagv);
    finalize_kernel<<<dim3(1), 256, 0, stream>>>(rowsum, colsum, diagv, out);
  }
}

// Round 3
// 262.131 us; speedup vs baseline: 2.5492x; 1.2014x over previous
//
#include <hip/hip_runtime.h>
#include <hip/hip_bf16.h>
#include <math.h>

#define NROWS 8192
#define DDIM  1024
#define BT    128
#define BK    64
#define MARGIN 0.3f

typedef __attribute__((ext_vector_type(4))) float  f32x4;
typedef __attribute__((ext_vector_type(8))) __bf16 bf16x8;

__device__ __forceinline__ unsigned f2bf_bits(float f) {
  unsigned u = __float_as_uint(f);
  u += 0x7fffu + ((u >> 16) & 1u);   // RNE
  return u >> 16;
}

// ============================ FAST PATH =====================================
// Kernel A: fused row-norm + bf16 convert; also zeroes rowsum/colsum so the
// launch needs no separate memset dispatch.
__global__ __launch_bounds__(256) void normconv_kernel(const float* __restrict__ x,
                                                       const float* __restrict__ y,
                                                       unsigned short* __restrict__ xn,
                                                       unsigned short* __restrict__ yn,
                                                       float* __restrict__ zero_base) {
  if (blockIdx.x < 16) {  // zero rowsum+colsum: 16384 floats = 16 blk * 256 thr * 4
    ((float4*)zero_base)[blockIdx.x * 256 + threadIdx.x] = (float4){0.f, 0.f, 0.f, 0.f};
  }
  int wid  = blockIdx.x * 4 + (threadIdx.x >> 6);   // one wave per row
  int lane = threadIdx.x & 63;
  const float* src;
  unsigned short* dst;
  int row;
  if (wid < NROWS) { src = x; dst = xn; row = wid; }
  else             { src = y; dst = yn; row = wid - NROWS; }
  const float4* p = (const float4*)(src + (size_t)row * DDIM);
  float4 v[4];
  float s = 0.f;
#pragma unroll
  for (int a = 0; a < 4; ++a) {
    v[a] = p[a * 64 + lane];
    s = fmaf(v[a].x, v[a].x, s); s = fmaf(v[a].y, v[a].y, s);
    s = fmaf(v[a].z, v[a].z, s); s = fmaf(v[a].w, v[a].w, s);
  }
#pragma unroll
  for (int m = 1; m < 64; m <<= 1) s += __shfl_xor(s, m, 64);
  float inv = 1.0f / fmaxf(sqrtf(s), 1e-8f);
  unsigned long long* d8 = (unsigned long long*)(dst + (size_t)row * DDIM);
#pragma unroll
  for (int a = 0; a < 4; ++a) {
    unsigned long long pk =
        (unsigned long long)f2bf_bits(v[a].x * inv) |
        ((unsigned long long)f2bf_bits(v[a].y * inv) << 16) |
        ((unsigned long long)f2bf_bits(v[a].z * inv) << 32) |
        ((unsigned long long)f2bf_bits(v[a].w * inv) << 48);
    d8[a * 64 + lane] = pk;
  }
}

// Kernel B: m97-style GEMM, XOR-swizzled LDS layout to kill the 16-way
// quad bank conflicts (row stride 128 B == full bank wrap).
// Physical LDS slot (row r, 16B-group p) holds logical k-group g = p ^ (r&7).
__global__ __launch_bounds__(256) void gemm_bf_kernel(const unsigned short* __restrict__ xn,
                                                      const unsigned short* __restrict__ yn,
                                                      float* __restrict__ rowsum,
                                                      float* __restrict__ colsum,
                                                      float* __restrict__ diagv) {
  __shared__ alignas(16) unsigned short As[BT * BK];
  __shared__ alignas(16) unsigned short Bs[BT * BK];
  __shared__ float red_row[BT];
  __shared__ float red_col[BT];

  const int tid  = threadIdx.x;
  const int bi   = blockIdx.y;
  const int bj   = blockIdx.x;
  const int lane = tid & 63;
  const int wave = tid >> 6;
  const int wr   = wave >> 1, wc = wave & 1;
  const int quad = lane >> 4, l15 = lane & 15;

  if (tid < BT) red_row[tid] = 0.f; else red_col[tid - BT] = 0.f;

  // staging: lane l -> local row (l>>3), SOURCE k-group (l&7)^(l>>3) (swizzle);
  // HW writes LDS at base + l*16, i.e. physical group l&7.
  const int r_l = lane >> 3;
  const int cg  = (lane & 7) ^ r_l;
  const unsigned short* ga =
      xn + (size_t)(bi * BT + wave * 32 + r_l) * DDIM + cg * 8;
  const unsigned short* gb =
      yn + (size_t)(bj * BT + wave * 32 + r_l) * DDIM + cg * 8;

  f32x4 acc[4][4];
#pragma unroll
  for (int i = 0; i < 4; ++i)
#pragma unroll
    for (int j = 0; j < 4; ++j) acc[i][j] = (f32x4){0.f, 0.f, 0.f, 0.f};

  for (int k0 = 0; k0 < DDIM; k0 += BK) {
#pragma unroll
    for (int a = 0; a < 4; ++a) {
      __builtin_amdgcn_global_load_lds(
          (const __attribute__((address_space(1))) unsigned int*)(ga + (size_t)a * 8 * DDIM + k0),
          (__attribute__((address_space(3))) unsigned int*)&As[(wave * 32 + a * 8) * BK],
          16, 0, 0);
      __builtin_amdgcn_global_load_lds(
          (const __attribute__((address_space(1))) unsigned int*)(gb + (size_t)a * 8 * DDIM + k0),
          (__attribute__((address_space(3))) unsigned int*)&Bs[(wave * 32 + a * 8) * BK],
          16, 0, 0);
    }
    __syncthreads();
#pragma unroll
    for (int kk = 0; kk < BK; kk += 32) {
      bf16x8 af[4], bf[4];
      const int pofs = (((kk >> 3) + quad) ^ (l15 & 7)) * 8;  // physical group
#pragma unroll
      for (int f = 0; f < 4; ++f) {
        af[f] = *(const bf16x8*)&As[(wr * 64 + f * 16 + l15) * BK + pofs];
        bf[f] = *(const bf16x8*)&Bs[(wc * 64 + f * 16 + l15) * BK + pofs];
      }
#pragma unroll
      for (int fr = 0; fr < 4; ++fr)
#pragma unroll
        for (int fc = 0; fc < 4; ++fc)
          acc[fr][fc] = __builtin_amdgcn_mfma_f32_16x16x32_bf16(af[fr], bf[fc], acc[fr][fc], 0, 0, 0);
    }
    __syncthreads();
  }

  // ---- epilogue (validated R1/R2) ----
  if (bi == bj && wr == wc && (l15 >> 2) == quad) {
    int r = l15 & 3;
#pragma unroll
    for (int f = 0; f < 4; ++f)
      diagv[bi * BT + wr * 64 + f * 16 + l15] = acc[f][f][r];
  }

  float racc[4][4];
  float cacc[4];
#pragma unroll
  for (int i = 0; i < 4; ++i) {
    cacc[i] = 0.f;
#pragma unroll
    for (int j = 0; j < 4; ++j) racc[i][j] = 0.f;
  }
#pragma unroll
  for (int fr = 0; fr < 4; ++fr)
#pragma unroll
    for (int fc = 0; fc < 4; ++fc) {
      f32x4 v = acc[fr][fc];
#pragma unroll
      for (int r = 0; r < 4; ++r) {
        float e = __expf(v[r]);
        racc[fr][r] += e;
        cacc[fc]    += e;
      }
    }
#pragma unroll
  for (int m = 1; m <= 8; m <<= 1)
#pragma unroll
    for (int fr = 0; fr < 4; ++fr)
#pragma unroll
      for (int r = 0; r < 4; ++r) racc[fr][r] += __shfl_xor(racc[fr][r], m, 64);
  if (l15 == 0)
#pragma unroll
    for (int fr = 0; fr < 4; ++fr)
#pragma unroll
      for (int r = 0; r < 4; ++r)
        atomicAdd(&red_row[wr * 64 + fr * 16 + quad * 4 + r], racc[fr][r]);
#pragma unroll
  for (int m = 16; m <= 32; m <<= 1)
#pragma unroll
    for (int fc = 0; fc < 4; ++fc) cacc[fc] += __shfl_xor(cacc[fc], m, 64);
  if (quad == 0)
#pragma unroll
    for (int fc = 0; fc < 4; ++fc)
      atomicAdd(&red_col[wc * 64 + fc * 16 + l15], cacc[fc]);

  __syncthreads();
  if (tid < BT) atomicAdd(&rowsum[bi * BT + tid], red_row[tid]);
  else          atomicAdd(&colsum[bj * BT + (tid - BT)], red_col[tid - BT]);
}

// ============================ FALLBACK PATH (R1, known-good) ================
__global__ __launch_bounds__(256) void norm_kernel(const float* __restrict__ x,
                                                   const float* __restrict__ y,
                                                   float* __restrict__ invn) {
  int wid  = (int)((blockIdx.x * blockDim.x + threadIdx.x) >> 6);
  int lane = threadIdx.x & 63;
  const float* src = (wid < NROWS) ? x : y;
  int row = (wid < NROWS) ? wid : (wid - NROWS);
  const float4* p = (const float4*)(src + (size_t)row * DDIM);
  float s = 0.f;
#pragma unroll
  for (int a = 0; a < 4; ++a) {
    float4 v = p[a * 64 + lane];
    s = fmaf(v.x, v.x, s); s = fmaf(v.y, v.y, s);
    s = fmaf(v.z, v.z, s); s = fmaf(v.w, v.w, s);
  }
#pragma unroll
  for (int m = 1; m < 64; m <<= 1) s += __shfl_xor(s, m, 64);
  if (lane == 0) invn[wid] = 1.0f / fmaxf(sqrtf(s), 1e-8f);
}

__global__ __launch_bounds__(256) void gemm_kernel(const float* __restrict__ x,
                                                   const float* __restrict__ y,
                                                   const float* __restrict__ invn,
                                                   float* __restrict__ rowsum,
                                                   float* __restrict__ colsum,
                                                   float* __restrict__ diagv) {
  __shared__ alignas(16) unsigned short As[BT * BK];
  __shared__ alignas(16) unsigned short Bs[BT * BK];
  __shared__ float red_row[BT];
  __shared__ float red_col[BT];

  const int tid  = threadIdx.x;
  const int bi   = blockIdx.y;
  const int bj   = blockIdx.x;
  const int lane = tid & 63;
  const int wave = tid >> 6;
  const int wr   = wave >> 1, wc = wave & 1;
  const int quad = lane >> 4, l15 = lane & 15;
  const int srow = tid >> 4;
  const int sc4  = tid & 15;

  if (tid < BT) red_row[tid] = 0.f; else red_col[tid - BT] = 0.f;

  float ainv[8], binv[8];
#pragma unroll
  for (int a = 0; a < 8; ++a) {
    ainv[a] = invn[bi * BT + a * 16 + srow];
    binv[a] = invn[NROWS + bj * BT + a * 16 + srow];
  }

  f32x4 acc[4][4];
#pragma unroll
  for (int i = 0; i < 4; ++i)
#pragma unroll
    for (int j = 0; j < 4; ++j) acc[i][j] = (f32x4){0.f, 0.f, 0.f, 0.f};

  for (int k0 = 0; k0 < DDIM; k0 += BK) {
#pragma unroll
    for (int a = 0; a < 8; ++a) {
      int row = a * 16 + srow;
      float4 va = *(const float4*)(x + (size_t)(bi * BT + row) * DDIM + k0 + sc4 * 4);
      float4 vb = *(const float4*)(y + (size_t)(bj * BT + row) * DDIM + k0 + sc4 * 4);
      float sa = ainv[a], sb = binv[a];
      unsigned long long pa =
          (unsigned long long)f2bf_bits(va.x * sa) |
          ((unsigned long long)f2bf_bits(va.y * sa) << 16) |
          ((unsigned long long)f2bf_bits(va.z * sa) << 32) |
          ((unsigned long long)f2bf_bits(va.w * sa) << 48);
      unsigned long long pb =
          (unsigned long long)f2bf_bits(vb.x * sb) |
          ((unsigned long long)f2bf_bits(vb.y * sb) << 16) |
          ((unsigned long long)f2bf_bits(vb.z * sb) << 32) |
          ((unsigned long long)f2bf_bits(vb.w * sb) << 48);
      *(unsigned long long*)&As[row * BK + sc4 * 4] = pa;
      *(unsigned long long*)&Bs[row * BK + sc4 * 4] = pb;
    }
    __syncthreads();
#pragma unroll
    for (int kk = 0; kk < BK; kk += 32) {
      bf16x8 af[4], bf[4];
#pragma unroll
      for (int f = 0; f < 4; ++f) {
        af[f] = *(const bf16x8*)&As[(wr * 64 + f * 16 + l15) * BK + kk + quad * 8];
        bf[f] = *(const bf16x8*)&Bs[(wc * 64 + f * 16 + l15) * BK + kk + quad * 8];
      }
#pragma unroll
      for (int fr = 0; fr < 4; ++fr)
#pragma unroll
        for (int fc = 0; fc < 4; ++fc)
          acc[fr][fc] = __builtin_amdgcn_mfma_f32_16x16x32_bf16(af[fr], bf[fc], acc[fr][fc], 0, 0, 0);
    }
    __syncthreads();
  }

  if (bi == bj && wr == wc && (l15 >> 2) == quad) {
    int r = l15 & 3;
#pragma unroll
    for (int f = 0; f < 4; ++f)
      diagv[bi * BT + wr * 64 + f * 16 + l15] = acc[f][f][r];
  }

  float racc[4][4];
  float cacc[4];
#pragma unroll
  for (int i = 0; i < 4; ++i) {
    cacc[i] = 0.f;
#pragma unroll
    for (int j = 0; j < 4; ++j) racc[i][j] = 0.f;
  }
#pragma unroll
  for (int fr = 0; fr < 4; ++fr)
#pragma unroll
    for (int fc = 0; fc < 4; ++fc) {
      f32x4 v = acc[fr][fc];
#pragma unroll
      for (int r = 0; r < 4; ++r) {
        float e = __expf(v[r]);
        racc[fr][r] += e;
        cacc[fc]    += e;
      }
    }
#pragma unroll
  for (int m = 1; m <= 8; m <<= 1)
#pragma unroll
    for (int fr = 0; fr < 4; ++fr)
#pragma unroll
      for (int r = 0; r < 4; ++r) racc[fr][r] += __shfl_xor(racc[fr][r], m, 64);
  if (l15 == 0)
#pragma unroll
    for (int fr = 0; fr < 4; ++fr)
#pragma unroll
      for (int r = 0; r < 4; ++r)
        atomicAdd(&red_row[wr * 64 + fr * 16 + quad * 4 + r], racc[fr][r]);
#pragma unroll
  for (int m = 16; m <= 32; m <<= 1)
#pragma unroll
    for (int fc = 0; fc < 4; ++fc) cacc[fc] += __shfl_xor(cacc[fc], m, 64);
  if (quad == 0)
#pragma unroll
    for (int fc = 0; fc < 4; ++fc)
      atomicAdd(&red_col[wc * 64 + fc * 16 + l15], cacc[fc]);

  __syncthreads();
  if (tid < BT) atomicAdd(&rowsum[bi * BT + tid], red_row[tid]);
  else          atomicAdd(&colsum[bj * BT + (tid - BT)], red_col[tid - BT]);
}

// ---------------- Final loss (shared by both paths) -------------------------
__global__ __launch_bounds__(1024) void finalize_kernel(const float* __restrict__ rowsum,
                                                        const float* __restrict__ colsum,
                                                        const float* __restrict__ diagv,
                                                        float* __restrict__ out) {
  float s = 0.f;
  for (int i = threadIdx.x; i < NROWS; i += 1024) {
    float d  = diagv[i];
    float ed = __expf(d);
    float m1 = __expf(d - MARGIN);
    float negR = rowsum[i] - ed;
    float negC = colsum[i] - ed;
    s += __logf((m1 + negR) / m1) + __logf((m1 + negC) / m1);
  }
  __shared__ float red[16];
#pragma unroll
  for (int m = 1; m < 64; m <<= 1) s += __shfl_xor(s, m, 64);
  if ((threadIdx.x & 63) == 0) red[threadIdx.x >> 6] = s;
  __syncthreads();
  if (threadIdx.x < 64) {
    float v = (threadIdx.x < 16) ? red[threadIdx.x] : 0.f;
#pragma unroll
    for (int m = 1; m < 16; m <<= 1) v += __shfl_xor(v, m, 64);
    if (threadIdx.x == 0) out[0] = v / (float)NROWS;
  }
}

extern "C" void kernel_launch(void* const* d_in, const int* in_sizes, int n_in,
                              void* d_out, int out_size, void* d_ws, size_t ws_size,
                              hipStream_t stream) {
  const float* x = (const float*)d_in[0];
  const float* y = (const float*)d_in[1];
  float* out = (float*)d_out;
  char* ws = (char*)d_ws;

  const size_t bf_bytes = (size_t)NROWS * DDIM * 2;          // 16 MB each
  const size_t need_fast = 2 * bf_bytes + 3 * NROWS * 4;     // ~32 MB + 96 KB

  if (ws_size >= need_fast) {
    unsigned short* xn = (unsigned short*)ws;
    unsigned short* yn = xn + (size_t)NROWS * DDIM;
    float* rowsum = (float*)(ws + 2 * bf_bytes);
    float* colsum = rowsum + NROWS;
    float* diagv  = colsum + NROWS;
    normconv_kernel<<<dim3((2 * NROWS) / 4), 256, 0, stream>>>(x, y, xn, yn, rowsum);
    gemm_bf_kernel<<<dim3(NROWS / BT, NROWS / BT), 256, 0, stream>>>(xn, yn, rowsum, colsum, diagv);
    finalize_kernel<<<dim3(1), 1024, 0, stream>>>(rowsum, colsum, diagv, out);
  } else {
    float* invn   = (float*)ws;
    float* rowsum = (float*)(ws + 16384 * 4);
    float* colsum = rowsum + NROWS;
    float* diagv  = colsum + NROWS;
    hipMemsetAsync(rowsum, 0, 2 * NROWS * sizeof(float), stream);
    norm_kernel<<<dim3((2 * NROWS) / 4 / 64), 256, 0, stream>>>(x, y, invn);
    gemm_kernel<<<dim3(NROWS / BT, NROWS / BT), 256, 0, stream>>>(x, y, invn, rowsum, colsum, diagv);
    finalize_kernel<<<dim3(1), 1024, 0, stream>>>(rowsum, colsum, diagv, out);
  }
}

// Round 4
// 190.716 us; speedup vs baseline: 3.5038x; 1.3745x over previous
//
#include <hip/hip_runtime.h>
#include <hip/hip_bf16.h>
#include <math.h>

#define NROWS 8192
#define DDIM  1024
#define BT    128
#define BKB   128      // K-bytes per tile in fp8 (= K elements)
#define MARGIN 0.3f
#define INV256 0.00390625f

typedef __attribute__((ext_vector_type(4))) float  f32x4;
typedef __attribute__((ext_vector_type(8))) __bf16 bf16x8;
typedef __attribute__((ext_vector_type(4))) int    i32x4;
typedef __attribute__((ext_vector_type(8))) int    i32x8;

__device__ __forceinline__ unsigned f2bf_bits(float f) {
  unsigned u = __float_as_uint(f);
  u += 0x7fffu + ((u >> 16) & 1u);   // RNE
  return u >> 16;
}

// ============================ FAST PATH (MX-fp8) ============================
// Kernel A: row-norm + fp8 e4m3 quantize of 16*xn; also zeroes rowsum/colsum.
__global__ __launch_bounds__(256) void normconv8_kernel(const float* __restrict__ x,
                                                        const float* __restrict__ y,
                                                        unsigned int* __restrict__ xq,
                                                        unsigned int* __restrict__ yq,
                                                        float* __restrict__ zero_base) {
  if (blockIdx.x < 16) {  // 16 blk * 256 thr * float4 = 16384 floats (rowsum+colsum)
    ((float4*)zero_base)[blockIdx.x * 256 + threadIdx.x] = (float4){0.f, 0.f, 0.f, 0.f};
  }
  int wid  = blockIdx.x * 4 + (threadIdx.x >> 6);   // one wave per row
  int lane = threadIdx.x & 63;
  const float* src;
  unsigned int* dst;
  int row;
  if (wid < NROWS) { src = x; dst = xq; row = wid; }
  else             { src = y; dst = yq; row = wid - NROWS; }
  const float4* p = (const float4*)(src + (size_t)row * DDIM);
  float4 v[4];
  float s = 0.f;
#pragma unroll
  for (int a = 0; a < 4; ++a) {
    v[a] = p[a * 64 + lane];
    s = fmaf(v[a].x, v[a].x, s); s = fmaf(v[a].y, v[a].y, s);
    s = fmaf(v[a].z, v[a].z, s); s = fmaf(v[a].w, v[a].w, s);
  }
#pragma unroll
  for (int m = 1; m < 64; m <<= 1) s += __shfl_xor(s, m, 64);
  // scale by 16 into fp8 to stay clear of e4m3 denormals; undone in epilogue
  float inv = 16.0f / fmaxf(sqrtf(s), 1e-8f);
  unsigned int* d4 = dst + (size_t)row * (DDIM / 4);
#pragma unroll
  for (int a = 0; a < 4; ++a) {
    int w = __builtin_amdgcn_cvt_pk_fp8_f32(v[a].x * inv, v[a].y * inv, 0, false);
    w     = __builtin_amdgcn_cvt_pk_fp8_f32(v[a].z * inv, v[a].w * inv, w, true);
    d4[a * 64 + lane] = (unsigned int)w;
  }
}

// Kernel B: MX-fp8 GEMM (16x16x128 f8f6f4, scales = 1.0), XOR-swizzled LDS,
// fused exp + row/col reduction + diag epilogue (C/D layout shape-determined,
// identical to the R1-validated bf16 epilogue; acc scaled by 1/256 first).
__global__ __launch_bounds__(256) void gemm_mx_kernel(const unsigned char* __restrict__ xq,
                                                      const unsigned char* __restrict__ yq,
                                                      float* __restrict__ rowsum,
                                                      float* __restrict__ colsum,
                                                      float* __restrict__ diagv) {
  __shared__ alignas(16) unsigned char As[BT * BKB];  // 16 KB
  __shared__ alignas(16) unsigned char Bs[BT * BKB];  // 16 KB
  __shared__ float red_row[BT];
  __shared__ float red_col[BT];

  const int tid  = threadIdx.x;
  const int bi   = blockIdx.y;
  const int bj   = blockIdx.x;
  const int lane = tid & 63;
  const int wave = tid >> 6;
  const int wr   = wave >> 1, wc = wave & 1;
  const int quad = lane >> 4, l15 = lane & 15;

  if (tid < BT) red_row[tid] = 0.f; else red_col[tid - BT] = 0.f;

  // staging: lane l -> local row (l>>3); SOURCE 16B-group (l&7)^(l>>3) so that
  // physical LDS group (l&7) holds logical group g = p ^ (row&7) (bank swizzle).
  const int r_l = lane >> 3;
  const int cg  = (lane & 7) ^ r_l;
  const unsigned char* ga = xq + (size_t)(bi * BT + wave * 32 + r_l) * DDIM + cg * 16;
  const unsigned char* gb = yq + (size_t)(bj * BT + wave * 32 + r_l) * DDIM + cg * 16;

  f32x4 acc[4][4];
#pragma unroll
  for (int i = 0; i < 4; ++i)
#pragma unroll
    for (int j = 0; j < 4; ++j) acc[i][j] = (f32x4){0.f, 0.f, 0.f, 0.f};

  const int r7 = l15 & 7;
  for (int k0 = 0; k0 < DDIM; k0 += BKB) {
#pragma unroll
    for (int a = 0; a < 4; ++a) {
      __builtin_amdgcn_global_load_lds(
          (const __attribute__((address_space(1))) unsigned int*)(ga + (size_t)a * 8 * DDIM + k0),
          (__attribute__((address_space(3))) unsigned int*)&As[(wave * 32 + a * 8) * BKB],
          16, 0, 0);
      __builtin_amdgcn_global_load_lds(
          (const __attribute__((address_space(1))) unsigned int*)(gb + (size_t)a * 8 * DDIM + k0),
          (__attribute__((address_space(3))) unsigned int*)&Bs[(wave * 32 + a * 8) * BKB],
          16, 0, 0);
    }
    __syncthreads();
    // A-frag: lane holds A[m=l15][k=quad*32+j], j=0..31 -> logical groups 2q,2q+1
    i32x8 af[4], bf[4];
#pragma unroll
    for (int f = 0; f < 4; ++f) {
      const unsigned char* ra = &As[(wr * 64 + f * 16 + l15) * BKB];
      const unsigned char* rb = &Bs[(wc * 64 + f * 16 + l15) * BKB];
      i32x4 alo = *(const i32x4*)(ra + (((quad * 2 + 0) ^ r7) * 16));
      i32x4 ahi = *(const i32x4*)(ra + (((quad * 2 + 1) ^ r7) * 16));
      i32x4 blo = *(const i32x4*)(rb + (((quad * 2 + 0) ^ r7) * 16));
      i32x4 bhi = *(const i32x4*)(rb + (((quad * 2 + 1) ^ r7) * 16));
      af[f] = (i32x8){alo.x, alo.y, alo.z, alo.w, ahi.x, ahi.y, ahi.z, ahi.w};
      bf[f] = (i32x8){blo.x, blo.y, blo.z, blo.w, bhi.x, bhi.y, bhi.z, bhi.w};
    }
#pragma unroll
    for (int fr = 0; fr < 4; ++fr)
#pragma unroll
      for (int fc = 0; fc < 4; ++fc)
        acc[fr][fc] = __builtin_amdgcn_mfma_scale_f32_16x16x128_f8f6f4(
            af[fr], bf[fc], acc[fr][fc],
            0, 0,                     // cbsz=FP8(e4m3), blgp=FP8(e4m3)
            0, 0x7F7F7F7F,            // opsel_a, scale_a (e8m0 127 = 1.0, all bytes)
            0, 0x7F7F7F7F);           // opsel_b, scale_b
    __syncthreads();
  }

  // ---- epilogue (R1-validated; acc *= 1/256 to undo the 16x16 prescale) ----
  if (bi == bj && wr == wc && (l15 >> 2) == quad) {
    int r = l15 & 3;
#pragma unroll
    for (int f = 0; f < 4; ++f)
      diagv[bi * BT + wr * 64 + f * 16 + l15] = acc[f][f][r] * INV256;
  }

  float racc[4][4];
  float cacc[4];
#pragma unroll
  for (int i = 0; i < 4; ++i) {
    cacc[i] = 0.f;
#pragma unroll
    for (int j = 0; j < 4; ++j) racc[i][j] = 0.f;
  }
#pragma unroll
  for (int fr = 0; fr < 4; ++fr)
#pragma unroll
    for (int fc = 0; fc < 4; ++fc) {
      f32x4 v = acc[fr][fc];
#pragma unroll
      for (int r = 0; r < 4; ++r) {
        float e = __expf(v[r] * INV256);
        racc[fr][r] += e;
        cacc[fc]    += e;
      }
    }
#pragma unroll
  for (int m = 1; m <= 8; m <<= 1)
#pragma unroll
    for (int fr = 0; fr < 4; ++fr)
#pragma unroll
      for (int r = 0; r < 4; ++r) racc[fr][r] += __shfl_xor(racc[fr][r], m, 64);
  if (l15 == 0)
#pragma unroll
    for (int fr = 0; fr < 4; ++fr)
#pragma unroll
      for (int r = 0; r < 4; ++r)
        atomicAdd(&red_row[wr * 64 + fr * 16 + quad * 4 + r], racc[fr][r]);
#pragma unroll
  for (int m = 16; m <= 32; m <<= 1)
#pragma unroll
    for (int fc = 0; fc < 4; ++fc) cacc[fc] += __shfl_xor(cacc[fc], m, 64);
  if (quad == 0)
#pragma unroll
    for (int fc = 0; fc < 4; ++fc)
      atomicAdd(&red_col[wc * 64 + fc * 16 + l15], cacc[fc]);

  __syncthreads();
  if (tid < BT) atomicAdd(&rowsum[bi * BT + tid], red_row[tid]);
  else          atomicAdd(&colsum[bj * BT + (tid - BT)], red_col[tid - BT]);
}

// ============================ FALLBACK PATH (R1, known-good) ================
__global__ __launch_bounds__(256) void norm_kernel(const float* __restrict__ x,
                                                   const float* __restrict__ y,
                                                   float* __restrict__ invn) {
  int wid  = (int)((blockIdx.x * blockDim.x + threadIdx.x) >> 6);
  int lane = threadIdx.x & 63;
  const float* src = (wid < NROWS) ? x : y;
  int row = (wid < NROWS) ? wid : (wid - NROWS);
  const float4* p = (const float4*)(src + (size_t)row * DDIM);
  float s = 0.f;
#pragma unroll
  for (int a = 0; a < 4; ++a) {
    float4 v = p[a * 64 + lane];
    s = fmaf(v.x, v.x, s); s = fmaf(v.y, v.y, s);
    s = fmaf(v.z, v.z, s); s = fmaf(v.w, v.w, s);
  }
#pragma unroll
  for (int m = 1; m < 64; m <<= 1) s += __shfl_xor(s, m, 64);
  if (lane == 0) invn[wid] = 1.0f / fmaxf(sqrtf(s), 1e-8f);
}

__global__ __launch_bounds__(256) void gemm_kernel(const float* __restrict__ x,
                                                   const float* __restrict__ y,
                                                   const float* __restrict__ invn,
                                                   float* __restrict__ rowsum,
                                                   float* __restrict__ colsum,
                                                   float* __restrict__ diagv) {
  __shared__ alignas(16) unsigned short As[BT * 64];
  __shared__ alignas(16) unsigned short Bs[BT * 64];
  __shared__ float red_row[BT];
  __shared__ float red_col[BT];

  const int tid  = threadIdx.x;
  const int bi   = blockIdx.y;
  const int bj   = blockIdx.x;
  const int lane = tid & 63;
  const int wave = tid >> 6;
  const int wr   = wave >> 1, wc = wave & 1;
  const int quad = lane >> 4, l15 = lane & 15;
  const int srow = tid >> 4;
  const int sc4  = tid & 15;

  if (tid < BT) red_row[tid] = 0.f; else red_col[tid - BT] = 0.f;

  float ainv[8], binv[8];
#pragma unroll
  for (int a = 0; a < 8; ++a) {
    ainv[a] = invn[bi * BT + a * 16 + srow];
    binv[a] = invn[NROWS + bj * BT + a * 16 + srow];
  }

  f32x4 acc[4][4];
#pragma unroll
  for (int i = 0; i < 4; ++i)
#pragma unroll
    for (int j = 0; j < 4; ++j) acc[i][j] = (f32x4){0.f, 0.f, 0.f, 0.f};

  for (int k0 = 0; k0 < DDIM; k0 += 64) {
#pragma unroll
    for (int a = 0; a < 8; ++a) {
      int row = a * 16 + srow;
      float4 va = *(const float4*)(x + (size_t)(bi * BT + row) * DDIM + k0 + sc4 * 4);
      float4 vb = *(const float4*)(y + (size_t)(bj * BT + row) * DDIM + k0 + sc4 * 4);
      float sa = ainv[a], sb = binv[a];
      unsigned long long pa =
          (unsigned long long)f2bf_bits(va.x * sa) |
          ((unsigned long long)f2bf_bits(va.y * sa) << 16) |
          ((unsigned long long)f2bf_bits(va.z * sa) << 32) |
          ((unsigned long long)f2bf_bits(va.w * sa) << 48);
      unsigned long long pb =
          (unsigned long long)f2bf_bits(vb.x * sb) |
          ((unsigned long long)f2bf_bits(vb.y * sb) << 16) |
          ((unsigned long long)f2bf_bits(vb.z * sb) << 32) |
          ((unsigned long long)f2bf_bits(vb.w * sb) << 48);
      *(unsigned long long*)&As[row * 64 + sc4 * 4] = pa;
      *(unsigned long long*)&Bs[row * 64 + sc4 * 4] = pb;
    }
    __syncthreads();
#pragma unroll
    for (int kk = 0; kk < 64; kk += 32) {
      bf16x8 af[4], bf[4];
#pragma unroll
      for (int f = 0; f < 4; ++f) {
        af[f] = *(const bf16x8*)&As[(wr * 64 + f * 16 + l15) * 64 + kk + quad * 8];
        bf[f] = *(const bf16x8*)&Bs[(wc * 64 + f * 16 + l15) * 64 + kk + quad * 8];
      }
#pragma unroll
      for (int fr = 0; fr < 4; ++fr)
#pragma unroll
        for (int fc = 0; fc < 4; ++fc)
          acc[fr][fc] = __builtin_amdgcn_mfma_f32_16x16x32_bf16(af[fr], bf[fc], acc[fr][fc], 0, 0, 0);
    }
    __syncthreads();
  }

  if (bi == bj && wr == wc && (l15 >> 2) == quad) {
    int r = l15 & 3;
#pragma unroll
    for (int f = 0; f < 4; ++f)
      diagv[bi * BT + wr * 64 + f * 16 + l15] = acc[f][f][r];
  }

  float racc[4][4];
  float cacc[4];
#pragma unroll
  for (int i = 0; i < 4; ++i) {
    cacc[i] = 0.f;
#pragma unroll
    for (int j = 0; j < 4; ++j) racc[i][j] = 0.f;
  }
#pragma unroll
  for (int fr = 0; fr < 4; ++fr)
#pragma unroll
    for (int fc = 0; fc < 4; ++fc) {
      f32x4 v = acc[fr][fc];
#pragma unroll
      for (int r = 0; r < 4; ++r) {
        float e = __expf(v[r]);
        racc[fr][r] += e;
        cacc[fc]    += e;
      }
    }
#pragma unroll
  for (int m = 1; m <= 8; m <<= 1)
#pragma unroll
    for (int fr = 0; fr < 4; ++fr)
#pragma unroll
      for (int r = 0; r < 4; ++r) racc[fr][r] += __shfl_xor(racc[fr][r], m, 64);
  if (l15 == 0)
#pragma unroll
    for (int fr = 0; fr < 4; ++fr)
#pragma unroll
      for (int r = 0; r < 4; ++r)
        atomicAdd(&red_row[wr * 64 + fr * 16 + quad * 4 + r], racc[fr][r]);
#pragma unroll
  for (int m = 16; m <= 32; m <<= 1)
#pragma unroll
    for (int fc = 0; fc < 4; ++fc) cacc[fc] += __shfl_xor(cacc[fc], m, 64);
  if (quad == 0)
#pragma unroll
    for (int fc = 0; fc < 4; ++fc)
      atomicAdd(&red_col[wc * 64 + fc * 16 + l15], cacc[fc]);

  __syncthreads();
  if (tid < BT) atomicAdd(&rowsum[bi * BT + tid], red_row[tid]);
  else          atomicAdd(&colsum[bj * BT + (tid - BT)], red_col[tid - BT]);
}

// ---------------- Final loss (shared by both paths) -------------------------
__global__ __launch_bounds__(1024) void finalize_kernel(const float* __restrict__ rowsum,
                                                        const float* __restrict__ colsum,
                                                        const float* __restrict__ diagv,
                                                        float* __restrict__ out) {
  float s = 0.f;
  for (int i = threadIdx.x; i < NROWS; i += 1024) {
    float d  = diagv[i];
    float ed = __expf(d);
    float m1 = __expf(d - MARGIN);
    float negR = rowsum[i] - ed;
    float negC = colsum[i] - ed;
    s += __logf((m1 + negR) / m1) + __logf((m1 + negC) / m1);
  }
  __shared__ float red[16];
#pragma unroll
  for (int m = 1; m < 64; m <<= 1) s += __shfl_xor(s, m, 64);
  if ((threadIdx.x & 63) == 0) red[threadIdx.x >> 6] = s;
  __syncthreads();
  if (threadIdx.x < 64) {
    float v = (threadIdx.x < 16) ? red[threadIdx.x] : 0.f;
#pragma unroll
    for (int m = 1; m < 16; m <<= 1) v += __shfl_xor(v, m, 64);
    if (threadIdx.x == 0) out[0] = v / (float)NROWS;
  }
}

extern "C" void kernel_launch(void* const* d_in, const int* in_sizes, int n_in,
                              void* d_out, int out_size, void* d_ws, size_t ws_size,
                              hipStream_t stream) {
  const float* x = (const float*)d_in[0];
  const float* y = (const float*)d_in[1];
  float* out = (float*)d_out;
  char* ws = (char*)d_ws;

  const size_t q_bytes = (size_t)NROWS * DDIM;               // 8 MB each (fp8)
  const size_t need_fast = 2 * q_bytes + 3 * NROWS * 4;      // ~16 MB + 96 KB

  if (ws_size >= need_fast) {
    unsigned int* xq = (unsigned int*)ws;
    unsigned int* yq = (unsigned int*)(ws + q_bytes);
    float* rowsum = (float*)(ws + 2 * q_bytes);
    float* colsum = rowsum + NROWS;
    float* diagv  = colsum + NROWS;
    normconv8_kernel<<<dim3((2 * NROWS) / 4), 256, 0, stream>>>(x, y, xq, yq, rowsum);
    gemm_mx_kernel<<<dim3(NROWS / BT, NROWS / BT), 256, 0, stream>>>(
        (const unsigned char*)xq, (const unsigned char*)yq, rowsum, colsum, diagv);
    finalize_kernel<<<dim3(1), 1024, 0, stream>>>(rowsum, colsum, diagv, out);
  } else {
    float* invn   = (float*)ws;
    float* rowsum = (float*)(ws + 16384 * 4);
    float* colsum = rowsum + NROWS;
    float* diagv  = colsum + NROWS;
    hipMemsetAsync(rowsum, 0, 2 * NROWS * sizeof(float), stream);
    norm_kernel<<<dim3((2 * NROWS) / 4 / 64), 256, 0, stream>>>(x, y, invn);
    gemm_kernel<<<dim3(NROWS / BT, NROWS / BT), 256, 0, stream>>>(x, y, invn, rowsum, colsum, diagv);
    finalize_kernel<<<dim3(1), 1024, 0, stream>>>(rowsum, colsum, diagv, out);
  }
}